// Round 11
// baseline (277.459 us; speedup 1.0000x reference)
//
#include <hip/hip_runtime.h>
#include <math.h>

#define Bn 128
#define Cn 64
#define Tn 500

typedef float v2f __attribute__((ext_vector_type(2)));

// ---- explicit packed-fp32 math (VOP3P). acc/a/b/c are v2f (VGPR pairs). ----
// acc += a * b            (elementwise)
#define PK_FMA(acc, a, b) \
  asm("v_pk_fma_f32 %0, %1, %2, %0 op_sel:[0,0,0] op_sel_hi:[1,1,1]" \
      : "+v"(acc) : "v"(a), "v"(b))
// acc += a * broadcast(b.lo)
#define PK_FMA_LO(acc, a, b) \
  asm("v_pk_fma_f32 %0, %1, %2, %0 op_sel:[0,0,0] op_sel_hi:[1,0,1]" \
      : "+v"(acc) : "v"(a), "v"(b))
// acc += a * broadcast(b.hi)
#define PK_FMA_HI(acc, a, b) \
  asm("v_pk_fma_f32 %0, %1, %2, %0 op_sel:[0,1,0] op_sel_hi:[1,1,1]" \
      : "+v"(acc) : "v"(a), "v"(b))
// d = a * b + c           (elementwise)
#define PK_FMA3(d, a, b, c) \
  asm("v_pk_fma_f32 %0, %1, %2, %3 op_sel:[0,0,0] op_sel_hi:[1,1,1]" \
      : "=v"(d) : "v"(a), "v"(b), "v"(c))
// d = a * b               (elementwise)
#define PK_MUL(d, a, b) \
  asm("v_pk_mul_f32 %0, %1, %2 op_sel:[0,0] op_sel_hi:[1,1]" \
      : "=v"(d) : "v"(a), "v"(b))
// acc += a                (elementwise)
#define PK_ADD(acc, a) \
  asm("v_pk_add_f32 %0, %1, %0 op_sel:[0,0] op_sel_hi:[1,1]" \
      : "+v"(acc) : "v"(a))

__device__ __forceinline__ v2f elu2(v2f v) {
  // elu(v) = exp(min(v,0)) - 1 + max(v,0)
  v2f z; z.x = 0.f; z.y = 0.f;
  v2f mn = __builtin_elementwise_min(v, z);
  v2f mx = __builtin_elementwise_max(v, z);
  v2f e; e.x = __expf(mn.x); e.y = __expf(mn.y);
  return e - 1.f + mx;
}

// ---------------------------------------------------------------------------
// Stage 1: EEG feature extractor (R8/R10 structure; hot loops in explicit
// v_pk_fma_f32). One block per signal.
__global__ __launch_bounds__(256) void feat_kernel(
    const float* __restrict__ x, const float* __restrict__ w_conv1,
    const float* __restrict__ bn1, const float* __restrict__ w_dw,
    const float* __restrict__ bn2, const float* __restrict__ w_sdw,
    const float* __restrict__ w_spw, const float* __restrict__ bn3,
    float* __restrict__ feats, float* __restrict__ gzero)
{
  __shared__ float xs[544];
  __shared__ v2f   wL[200];
  __shared__ v2f   s1p[8 * 522];
  __shared__ float red[64];
  const int n = blockIdx.x;
  const int tid = threadIdx.x;
  const int op = tid & 7;
  const int tg = tid >> 3;
  const int T0 = tg * 16;

  if (n == 0 && tid < 64) gzero[tid] = 0.f;   // zero gsum1|gsum2

  if (tid < 125) *(float4*)&xs[16 + 4 * tid] = ((const float4*)(x + n * Tn))[tid];
  if (tid < 16) xs[tid] = 0.f;
  else if (tid < 44) xs[500 + tid] = 0.f;
  if (tid < 200) {
    int kk = tid % 25, opp = tid / 25;
    v2f w; w.x = w_conv1[opp * 50 + kk]; w.y = w_conv1[opp * 50 + 25 + kk];
    wL[opp * 25 + kk] = w;
  }

  v2f sc1, sh1, sc2, sh2, sc3, sh3;
  {
    int c0 = 2 * op, c1 = 2 * op + 1;
    sc1.x = bn1[c0] * rsqrtf(bn1[48 + c0] + 1e-5f);
    sc1.y = bn1[c1] * rsqrtf(bn1[48 + c1] + 1e-5f);
    sh1.x = bn1[16 + c0] - bn1[32 + c0] * sc1.x;
    sh1.y = bn1[16 + c1] - bn1[32 + c1] * sc1.y;
    sc2.x = bn2[c0] * rsqrtf(bn2[48 + c0] + 1e-5f);
    sc2.y = bn2[c1] * rsqrtf(bn2[48 + c1] + 1e-5f);
    sh2.x = bn2[16 + c0] - bn2[32 + c0] * sc2.x;
    sh2.y = bn2[16 + c1] - bn2[32 + c1] * sc2.y;
  }
  v2f wd[3], we[3];
#pragma unroll
  for (int k = 0; k < 3; ++k) {
    wd[k].x = w_dw[6 * op + k];     wd[k].y = w_dw[6 * op + 3 + k];
    we[k].x = w_sdw[6 * op + k];    we[k].y = w_sdw[6 * op + 3 + k];
  }
  __syncthreads();

  // ---- conv1 (K=25) over extended t in [T0-2, T0+18) ----
  float xw[48];
#pragma unroll
  for (int i = 0; i < 12; ++i) *(float4*)&xw[4 * i] = *(const float4*)&xs[T0 + 4 * i];
  const v2f* xp = (const v2f*)xw;   // xp[i] = {xw[2i], xw[2i+1]}, pair-aligned
  v2f ce[20];
#pragma unroll
  for (int j = 0; j < 20; ++j) { ce[j].x = 0.f; ce[j].y = 0.f; }
#pragma unroll
  for (int k = 0; k < 25; ++k) {
    v2f wt = wL[op * 25 + k];
#pragma unroll
    for (int j = 0; j < 20; ++j) {
      const int idx = j + k + 2;
      if (idx & 1) { PK_FMA_HI(ce[j], wt, xp[idx >> 1]); }
      else         { PK_FMA_LO(ce[j], wt, xp[idx >> 1]); }
    }
  }
  v2f zero; zero.x = 0.f; zero.y = 0.f;
#pragma unroll
  for (int j = 0; j < 20; ++j) {
    int t = T0 - 2 + j;
    v2f bnv;
    PK_FMA3(bnv, ce[j], sc1, sh1);
    v2f v = elu2(bnv);
    ce[j] = ((unsigned)t < (unsigned)Tn) ? v : zero;
  }

  // ---- depthwise K=3 + BN + ELU, t in [T0-1, T0+17) ----
  v2f d[18];
#pragma unroll
  for (int j = 0; j < 18; ++j) {
    int t = T0 - 1 + j;
    v2f a;
    PK_MUL(a, ce[j], wd[0]);
    PK_FMA(a, ce[j + 1], wd[1]);
    PK_FMA(a, ce[j + 2], wd[2]);
    v2f bnv;
    PK_FMA3(bnv, a, sc2, sh2);
    v2f v = elu2(bnv);
    d[j] = ((unsigned)t < (unsigned)Tn) ? v : zero;
  }

  // ---- separable depthwise K=3 (no act) -> LDS ----
#pragma unroll
  for (int r = 0; r < 8; ++r) {
    v2f s0, s1;
    PK_MUL(s0, d[2 * r], we[0]);
    PK_FMA(s0, d[2 * r + 1], we[1]);
    PK_FMA(s0, d[2 * r + 2], we[2]);
    PK_MUL(s1, d[2 * r + 1], we[0]);
    PK_FMA(s1, d[2 * r + 2], we[1]);
    PK_FMA(s1, d[2 * r + 3], we[2]);
    float4 st; st.x = s0.x; st.y = s0.y; st.z = s1.x; st.w = s1.y;
    *(float4*)&s1p[op * 522 + T0 + 2 * r] = st;
  }

  // ---- pointwise 16->16 + BN + ELU + t-sum ----
  const int oq = tid & 3, tgp = tid >> 2;
  v2f wA[16], wB[16];
#pragma unroll
  for (int q = 0; q < 16; ++q) {
    wA[q].x = w_spw[(4 * oq) * 16 + q];     wA[q].y = w_spw[(4 * oq + 1) * 16 + q];
    wB[q].x = w_spw[(4 * oq + 2) * 16 + q]; wB[q].y = w_spw[(4 * oq + 3) * 16 + q];
  }
  {
    int c0 = 4 * oq;
    sc3.x = bn3[c0] * rsqrtf(bn3[48 + c0] + 1e-5f);
    sc3.y = bn3[c0 + 1] * rsqrtf(bn3[48 + c0 + 1] + 1e-5f);
    sh3.x = bn3[16 + c0] - bn3[32 + c0] * sc3.x;
    sh3.y = bn3[16 + c0 + 1] - bn3[32 + c0 + 1] * sc3.y;
  }
  v2f sc3b, sh3b;
  {
    int c0 = 4 * oq + 2;
    sc3b.x = bn3[c0] * rsqrtf(bn3[48 + c0] + 1e-5f);
    sc3b.y = bn3[c0 + 1] * rsqrtf(bn3[48 + c0 + 1] + 1e-5f);
    sh3b.x = bn3[16 + c0] - bn3[32 + c0] * sc3b.x;
    sh3b.y = bn3[16 + c0 + 1] - bn3[32 + c0 + 1] * sc3b.y;
  }
  v2f tsA = zero, tsB = zero;
  __syncthreads();
#pragma unroll
  for (int tt = 0; tt < 8; ++tt) {
    int t = tgp + 64 * tt;
    if (tt < 7 || tgp < Tn - 448) {
      v2f aA = zero, aB = zero;
#pragma unroll
      for (int opr = 0; opr < 8; ++opr) {
        v2f inq = s1p[opr * 522 + t];
        PK_FMA_LO(aA, wA[2 * opr], inq);
        PK_FMA_HI(aA, wA[2 * opr + 1], inq);
        PK_FMA_LO(aB, wB[2 * opr], inq);
        PK_FMA_HI(aB, wB[2 * opr + 1], inq);
      }
      v2f bA, bB;
      PK_FMA3(bA, aA, sc3, sh3);
      PK_FMA3(bB, aB, sc3b, sh3b);
      v2f eA = elu2(bA);
      v2f eB = elu2(bB);
      PK_ADD(tsA, eA);
      PK_ADD(tsB, eB);
    }
  }
#pragma unroll
  for (int dd = 4; dd <= 32; dd <<= 1) {
    tsA.x += __shfl_xor(tsA.x, dd, 64); tsA.y += __shfl_xor(tsA.y, dd, 64);
    tsB.x += __shfl_xor(tsB.x, dd, 64); tsB.y += __shfl_xor(tsB.y, dd, 64);
  }
  if ((tid & 63) < 4) {
    float4 st; st.x = tsA.x; st.y = tsA.y; st.z = tsB.x; st.w = tsB.y;
    *(float4*)&red[(tid >> 6) * 16 + oq * 4] = st;
  }
  __syncthreads();
  if (tid < 16)
    feats[n * 16 + tid] =
        (red[tid] + red[16 + tid] + red[32 + tid] + red[48 + tid]) * (1.f / 500.f);
}

// ---------------------------------------------------------------------------
// GAT layer (R6/R10 structure — best-measured tail). Grid 256 = (b, i-half);
// block 512 = (head-half th) x 256. Fused per-block graph build.
template <int FIN, int LAYER>
__global__ __launch_bounds__(512) void gat_kernel(
    const float* __restrict__ Xa,
    const float* __restrict__ node_embed, const int* __restrict__ edges,
    const float* __restrict__ se_w1, const float* __restrict__ se_w2,
    const float* __restrict__ gsum_in,
    const float* __restrict__ W, const float* __restrict__ a_src,
    const float* __restrict__ a_dst, const float* __restrict__ bias,
    const float* __restrict__ bnp, const float* __restrict__ skip_w,
    float* __restrict__ out, float* __restrict__ gsum_out)
{
  constexpr int XLS = 0;
  constexpr int AL  = 8448;
  constexpr int MLG = AL + 4224;
  constexpr int XS  = MLG + 2112;
  constexpr int SS  = XS + 64 * FIN;
  constexpr int DS  = SS + 256;
  constexpr int CMB = DS + 128;
  constexpr int RS  = CMB + 1024;
  constexpr int SEA = RS + 32;
  constexpr int GT  = SEA + 32;
  constexpr int R8  = GT + 32;
  constexpr int TOT = R8 + 8;
  __shared__ float sm[TOT];

  const int b = blockIdx.x >> 1;
  const int i0 = (blockIdx.x & 1) * 32;
  const int tid = threadIdx.x;
  const int th = tid >> 8;
  const int tl = tid & 255;

  if (tid < 32) sm[SEA + tid] = 0.f;
  if (LAYER == 2 && tid >= 32 && tid < 64)
    sm[GT + tid - 32] = gsum_in[tid - 32] * (1.f / 8192.f);
  for (int i = tid; i < 1024; i += 512) sm[XLS + i] = node_embed[i];
  for (int i = tid; i < 2112; i += 512) sm[MLG + i] = 0.f;
  for (int i = tid; i < 64 * FIN; i += 512) sm[XS + i] = Xa[b * 64 * FIN + i];
  int e0 = 0, e1 = 0;
  if (tid < 256) { e0 = edges[tid]; e1 = edges[256 + tid]; }
  __syncthreads();

  for (int idx = tid; idx < 2048; idx += 512) {
    int ir = idx >> 6, j = idx & 63;
    const float* ni = sm + XLS + (i0 + ir) * 16;
    const float* nj = sm + XLS + j * 16;
    float a = 0.f;
#pragma unroll
    for (int f = 0; f < 16; ++f) a += ni[f] * nj[f];
    sm[AL + ir * 66 + j] = a > 0.f ? a : 0.f;
  }
  if (tid < 256 && e0 >= i0 && e0 < i0 + 32)
    atomicAdd(&sm[MLG + (e0 - i0) * 66 + e1], 1.f);
  if (LAYER == 2 && tid >= 256 && tid < 264) {
    float a = 0.f;
    for (int f = 0; f < 32; ++f) a += sm[GT + f] * se_w1[(tid - 256) * 32 + f];
    sm[R8 + tid - 256] = fmaxf(a, 0.f);
  }
  __syncthreads();

  if (tid < 32) {
    float s = 0.f;
    for (int j = 0; j < 64; ++j) s += sm[AL + tid * 66 + j];
    sm[RS + tid] = s + 1e-6f;
  }
  if (LAYER == 2 && tid >= 256 && tid < 288) {
    float a = 0.f;
    for (int k = 0; k < 8; ++k) a += sm[R8 + k] * se_w2[(tid - 256) * 8 + k];
    sm[GT + tid - 256] = 1.f / (1.f + __expf(-a));
  }
  __syncthreads();

  for (int idx = tid; idx < 2048; idx += 512) {
    int ir = idx >> 6, j = idx & 63;
    float dyn = (sm[AL + ir * 66 + j] / sm[RS + ir] > 0.1f) ? 1.f : 0.f;
    float M = (i0 + ir == j) ? 1.f : (sm[MLG + ir * 66 + j] + dyn);
    sm[MLG + ir * 66 + j] = (M > 0.f) ? __logf(M) : -INFINITY;
  }
  if (LAYER == 2) {
    for (int i = tid; i < 64 * FIN; i += 512) sm[XS + i] *= sm[GT + (i & 31)];
  }
  __syncthreads();

  {
    const int fo = tid & 127, q4r = tid >> 7;
    float wcol[FIN];
#pragma unroll
    for (int q = 0; q < FIN; ++q) wcol[q] = W[q * 128 + fo];
    for (int nn = q4r; nn < 64; nn += 4) {
      float acc = 0.f;
#pragma unroll
      for (int q = 0; q < FIN; ++q) acc += sm[XS + nn * FIN + q] * wcol[q];
      sm[XLS + nn * 132 + fo] = acc;
    }
  }
  __syncthreads();

  if (tid < 256) {
    const int nn = tid >> 2, h = tid & 3;
    float s = 0.f;
    for (int q = 0; q < 32; ++q)
      s += sm[XLS + nn * 132 + h * 32 + q] * a_src[h * 32 + q];
    sm[SS + h * 64 + nn] = s;
  } else if (tid < 384) {
    const int idx = tid - 256, ir = idx >> 2, h = idx & 3;
    float dv = 0.f;
    for (int q = 0; q < 32; ++q)
      dv += sm[XLS + (i0 + ir) * 132 + h * 32 + q] * a_dst[h * 32 + q];
    sm[DS + ir * 4 + h] = dv;
  }
  __syncthreads();

  const int ir = tl >> 3;
  const int q4 = tl & 7;
  float* alw = sm + AL + th * 2112;
  float accT[4] = {0.f, 0.f, 0.f, 0.f};
#pragma unroll
  for (int hh = 0; hh < 2; ++hh) {
    const int h = hh * 2 + th;
    const float dterm = sm[DS + ir * 4 + h];
    float lg[8];
    float mx = -INFINITY;
#pragma unroll
    for (int k = 0; k < 8; ++k) {
      int j = q4 * 8 + k;
      float e = dterm + sm[SS + h * 64 + j];
      e = e >= 0.f ? e : 0.2f * e;
      float v = e + sm[MLG + ir * 66 + j];
      lg[k] = v;
      mx = fmaxf(mx, v);
    }
    mx = fmaxf(mx, __shfl_xor(mx, 1, 8));
    mx = fmaxf(mx, __shfl_xor(mx, 2, 8));
    mx = fmaxf(mx, __shfl_xor(mx, 4, 8));
    float sum = 0.f;
#pragma unroll
    for (int k = 0; k < 8; ++k) { lg[k] = __expf(lg[k] - mx); sum += lg[k]; }
    sum += __shfl_xor(sum, 1, 8);
    sum += __shfl_xor(sum, 2, 8);
    sum += __shfl_xor(sum, 4, 8);
    const float inv = 1.f / sum;
#pragma unroll
    for (int k = 0; k < 8; ++k) alw[ir * 66 + q4 * 8 + k] = lg[k];
    float a0 = 0.f, a1 = 0.f, a2 = 0.f, a3 = 0.f;
#pragma unroll 8
    for (int j = 0; j < 64; ++j) {
      float av = alw[ir * 66 + j];
      float4 xv = *(const float4*)&sm[XLS + j * 132 + h * 32 + q4 * 4];
      a0 += av * xv.x; a1 += av * xv.y; a2 += av * xv.z; a3 += av * xv.w;
    }
    accT[0] += a0 * inv; accT[1] += a1 * inv;
    accT[2] += a2 * inv; accT[3] += a3 * inv;
  }

  if (th == 1) *(float4*)&sm[CMB + tl * 4] = make_float4(accT[0], accT[1], accT[2], accT[3]);
  __syncthreads();
  if (th == 0) {
    const float4 other = *(const float4*)&sm[CMB + tl * 4];
    accT[0] += other.x; accT[1] += other.y; accT[2] += other.z; accT[3] += other.w;
    const int i = i0 + ir;
    float res[4];
#pragma unroll
    for (int r = 0; r < 4; ++r) {
      int f = q4 * 4 + r;
      float bsc = bnp[f] * rsqrtf(bnp[96 + f] + 1e-5f);
      float bsh = bnp[32 + f] - bnp[64 + f] * bsc;
      float v = accT[r] * 0.25f + bias[f];
      v = v * bsc + bsh;
      float skip;
      if (LAYER == 1) {
        skip = 0.f;
#pragma unroll
        for (int q = 0; q < 16; ++q) skip += sm[XS + i * 16 + q] * skip_w[f * 16 + q];
      } else {
        skip = sm[XS + i * 32 + f];
      }
      v += skip;
      v = 0.5f * v * (1.f + erff(v * 0.70710678118654752440f));
      res[r] = v;
      atomicAdd(&sm[SEA + f], v);
    }
    *(float4*)&out[(b * 64 + i) * 32 + q4 * 4] = make_float4(res[0], res[1], res[2], res[3]);
  }
  __syncthreads();
  if (tid < 32) atomicAdd(&gsum_out[tid], sm[SEA + tid]);
}

// ---------------------------------------------------------------------------
// SE2 gate (redundant per block) + pool over C + classifier.
__global__ __launch_bounds__(64) void out_kernel(
    const float* __restrict__ tmp2, const float* __restrict__ gsum2,
    const float* __restrict__ se_w1, const float* __restrict__ se_w2,
    const float* __restrict__ clf_w, const float* __restrict__ clf_b,
    float* __restrict__ outp)
{
  __shared__ float mean32[32], r8[8], gate[32], pl[32];
  const int b = blockIdx.x, tid = threadIdx.x;
  if (tid < 32) mean32[tid] = gsum2[tid] * (1.f / 8192.f);
  __syncthreads();
  if (tid < 8) {
    float a = 0.f;
    for (int f = 0; f < 32; ++f) a += mean32[f] * se_w1[tid * 32 + f];
    r8[tid] = a > 0.f ? a : 0.f;
  }
  __syncthreads();
  if (tid < 32) {
    float a = 0.f;
    for (int k = 0; k < 8; ++k) a += r8[k] * se_w2[tid * 8 + k];
    gate[tid] = 1.f / (1.f + __expf(-a));
  }
  __syncthreads();
  if (tid < 32) {
    float a = 0.f;
    for (int n = 0; n < 64; ++n) a += tmp2[(b * 64 + n) * 32 + tid];
    pl[tid] = a * (1.f / 64.f) * gate[tid];
  }
  __syncthreads();
  if (tid < 2) {
    float a = clf_b[tid];
    for (int f = 0; f < 32; ++f) a += pl[f] * clf_w[tid * 32 + f];
    outp[b * 2 + tid] = a;
  }
}

// ---------------------------------------------------------------------------
extern "C" void kernel_launch(void* const* d_in, const int* in_sizes, int n_in,
                              void* d_out, int out_size, void* d_ws, size_t ws_size,
                              hipStream_t stream)
{
  const float* x          = (const float*)d_in[0];
  const int*   edges      = (const int*)d_in[1];
  const float* conv1_w    = (const float*)d_in[2];
  const float* bn_c1      = (const float*)d_in[3];
  const float* dw_w       = (const float*)d_in[4];
  const float* bn_c2      = (const float*)d_in[5];
  const float* sdw_w      = (const float*)d_in[6];
  const float* spw_w      = (const float*)d_in[7];
  const float* bn_c3      = (const float*)d_in[8];
  const float* node_embed = (const float*)d_in[9];
  const float* gat1_w     = (const float*)d_in[10];
  const float* gat1_asrc  = (const float*)d_in[11];
  const float* gat1_adst  = (const float*)d_in[12];
  const float* gat1_bias  = (const float*)d_in[13];
  const float* bn_g1      = (const float*)d_in[14];
  const float* skip1_w    = (const float*)d_in[15];
  const float* se1_w1     = (const float*)d_in[16];
  const float* se1_w2     = (const float*)d_in[17];
  const float* gat2_w     = (const float*)d_in[18];
  const float* gat2_asrc  = (const float*)d_in[19];
  const float* gat2_adst  = (const float*)d_in[20];
  const float* gat2_bias  = (const float*)d_in[21];
  const float* bn_g2      = (const float*)d_in[22];
  const float* se2_w1     = (const float*)d_in[23];
  const float* se2_w2     = (const float*)d_in[24];
  const float* clf_w      = (const float*)d_in[25];
  const float* clf_b      = (const float*)d_in[26];

  float* ws    = (float*)d_ws;
  float* feats = ws;             // 131072 floats  [B*C, 16]
  float* tmp1  = ws + 131072;    // 262144         [B*C, 32]
  float* tmp2  = ws + 393216;    // 262144         [B*C, 32]
  float* gs    = ws + 655360;    // 64: gsum1[32] | gsum2[32]

  feat_kernel<<<Bn * Cn, 256, 0, stream>>>(x, conv1_w, bn_c1, dw_w, bn_c2,
                                           sdw_w, spw_w, bn_c3, feats, gs);
  gat_kernel<16, 1><<<Bn * 2, 512, 0, stream>>>(
      feats, node_embed, edges, nullptr, nullptr, nullptr,
      gat1_w, gat1_asrc, gat1_adst, gat1_bias, bn_g1, skip1_w, tmp1, gs);
  gat_kernel<32, 2><<<Bn * 2, 512, 0, stream>>>(
      tmp1, node_embed, edges, se1_w1, se1_w2, gs,
      gat2_w, gat2_asrc, gat2_adst, gat2_bias, bn_g2, nullptr, tmp2, gs + 32);
  out_kernel<<<Bn, 64, 0, stream>>>(tmp2, gs + 32, se2_w1, se2_w2, clf_w, clf_b,
                                    (float*)d_out);
}

// Round 12
// 269.684 us; speedup vs baseline: 1.0288x; 1.0288x over previous
//
#include <hip/hip_runtime.h>
#include <math.h>

#define Bn 128
#define Cn 64
#define Tn 500

typedef float v2f __attribute__((ext_vector_type(2)));

__device__ __forceinline__ v2f elu2(v2f v) {
  // elu(v) = exp(min(v,0)) - 1 + max(v,0)   (branch/select-free, packable)
  v2f z; z.x = 0.f; z.y = 0.f;
  v2f mn = __builtin_elementwise_min(v, z);
  v2f mx = __builtin_elementwise_max(v, z);
  v2f e; e.x = __expf(mn.x); e.y = __expf(mn.y);
  return e - 1.f + mx;
}

// ---------------------------------------------------------------------------
// Stage 1: EEG feature extractor (R8 structure: no min-waves bound).
// One block per signal. Compiler already emits packed fp32 (verified R11:
// forcing v_pk_* via asm regressed) — leave the v2f expressions to it.
__global__ __launch_bounds__(256) void feat_kernel(
    const float* __restrict__ x, const float* __restrict__ w_conv1,
    const float* __restrict__ bn1, const float* __restrict__ w_dw,
    const float* __restrict__ bn2, const float* __restrict__ w_sdw,
    const float* __restrict__ w_spw, const float* __restrict__ bn3,
    float* __restrict__ feats, float* __restrict__ gzero)
{
  __shared__ float xs[544];
  __shared__ v2f   wL[200];
  __shared__ v2f   s1p[8 * 522];
  __shared__ float red[64];
  const int n = blockIdx.x;
  const int tid = threadIdx.x;
  const int op = tid & 7;
  const int tg = tid >> 3;
  const int T0 = tg * 16;

  if (n == 0 && tid < 64) gzero[tid] = 0.f;   // zero gsum1|gsum2

  if (tid < 125) *(float4*)&xs[16 + 4 * tid] = ((const float4*)(x + n * Tn))[tid];
  if (tid < 16) xs[tid] = 0.f;
  else if (tid < 44) xs[500 + tid] = 0.f;
  if (tid < 200) {
    int kk = tid % 25, opp = tid / 25;
    v2f w; w.x = w_conv1[opp * 50 + kk]; w.y = w_conv1[opp * 50 + 25 + kk];
    wL[opp * 25 + kk] = w;
  }

  v2f sc1, sh1, sc2, sh2, sc3, sh3;
  {
    int c0 = 2 * op, c1 = 2 * op + 1;
    sc1.x = bn1[c0] * rsqrtf(bn1[48 + c0] + 1e-5f);
    sc1.y = bn1[c1] * rsqrtf(bn1[48 + c1] + 1e-5f);
    sh1.x = bn1[16 + c0] - bn1[32 + c0] * sc1.x;
    sh1.y = bn1[16 + c1] - bn1[32 + c1] * sc1.y;
    sc2.x = bn2[c0] * rsqrtf(bn2[48 + c0] + 1e-5f);
    sc2.y = bn2[c1] * rsqrtf(bn2[48 + c1] + 1e-5f);
    sh2.x = bn2[16 + c0] - bn2[32 + c0] * sc2.x;
    sh2.y = bn2[16 + c1] - bn2[32 + c1] * sc2.y;
  }
  v2f wd[3], we[3];
#pragma unroll
  for (int k = 0; k < 3; ++k) {
    wd[k].x = w_dw[6 * op + k];     wd[k].y = w_dw[6 * op + 3 + k];
    we[k].x = w_sdw[6 * op + k];    we[k].y = w_sdw[6 * op + 3 + k];
  }
  __syncthreads();

  float xw[48];
#pragma unroll
  for (int i = 0; i < 12; ++i) *(float4*)&xw[4 * i] = *(const float4*)&xs[T0 + 4 * i];
  v2f ce[20];
#pragma unroll
  for (int j = 0; j < 20; ++j) { ce[j].x = 0.f; ce[j].y = 0.f; }
#pragma unroll
  for (int k = 0; k < 25; ++k) {
    v2f wt = wL[op * 25 + k];
#pragma unroll
    for (int j = 0; j < 20; ++j) ce[j] += wt * xw[j + k + 2];
  }
  v2f zero; zero.x = 0.f; zero.y = 0.f;
#pragma unroll
  for (int j = 0; j < 20; ++j) {
    int t = T0 - 2 + j;
    v2f v = elu2(ce[j] * sc1 + sh1);
    ce[j] = ((unsigned)t < (unsigned)Tn) ? v : zero;
  }

  v2f d[18];
#pragma unroll
  for (int j = 0; j < 18; ++j) {
    int t = T0 - 1 + j;
    v2f a = ce[j] * wd[0] + ce[j + 1] * wd[1] + ce[j + 2] * wd[2];
    v2f v = elu2(a * sc2 + sh2);
    d[j] = ((unsigned)t < (unsigned)Tn) ? v : zero;
  }

#pragma unroll
  for (int r = 0; r < 8; ++r) {
    v2f s0 = d[2 * r] * we[0] + d[2 * r + 1] * we[1] + d[2 * r + 2] * we[2];
    v2f s1 = d[2 * r + 1] * we[0] + d[2 * r + 2] * we[1] + d[2 * r + 3] * we[2];
    float4 st; st.x = s0.x; st.y = s0.y; st.z = s1.x; st.w = s1.y;
    *(float4*)&s1p[op * 522 + T0 + 2 * r] = st;
  }

  const int oq = tid & 3, tgp = tid >> 2;
  v2f wA[16], wB[16];
#pragma unroll
  for (int q = 0; q < 16; ++q) {
    wA[q].x = w_spw[(4 * oq) * 16 + q];     wA[q].y = w_spw[(4 * oq + 1) * 16 + q];
    wB[q].x = w_spw[(4 * oq + 2) * 16 + q]; wB[q].y = w_spw[(4 * oq + 3) * 16 + q];
  }
  {
    int c0 = 4 * oq;
    sc3.x = bn3[c0] * rsqrtf(bn3[48 + c0] + 1e-5f);
    sc3.y = bn3[c0 + 1] * rsqrtf(bn3[48 + c0 + 1] + 1e-5f);
    sh3.x = bn3[16 + c0] - bn3[32 + c0] * sc3.x;
    sh3.y = bn3[16 + c0 + 1] - bn3[32 + c0 + 1] * sc3.y;
  }
  v2f sc3b, sh3b;
  {
    int c0 = 4 * oq + 2;
    sc3b.x = bn3[c0] * rsqrtf(bn3[48 + c0] + 1e-5f);
    sc3b.y = bn3[c0 + 1] * rsqrtf(bn3[48 + c0 + 1] + 1e-5f);
    sh3b.x = bn3[16 + c0] - bn3[32 + c0] * sc3b.x;
    sh3b.y = bn3[16 + c0 + 1] - bn3[32 + c0 + 1] * sc3b.y;
  }
  v2f tsA = zero, tsB = zero;
  __syncthreads();
#pragma unroll
  for (int tt = 0; tt < 8; ++tt) {
    int t = tgp + 64 * tt;
    if (tt < 7 || tgp < Tn - 448) {
      v2f aA = zero, aB = zero;
#pragma unroll
      for (int opr = 0; opr < 8; ++opr) {
        v2f inq = s1p[opr * 522 + t];
        aA += wA[2 * opr] * inq.x;  aA += wA[2 * opr + 1] * inq.y;
        aB += wB[2 * opr] * inq.x;  aB += wB[2 * opr + 1] * inq.y;
      }
      tsA += elu2(aA * sc3 + sh3);
      tsB += elu2(aB * sc3b + sh3b);
    }
  }
#pragma unroll
  for (int dd = 4; dd <= 32; dd <<= 1) {
    tsA.x += __shfl_xor(tsA.x, dd, 64); tsA.y += __shfl_xor(tsA.y, dd, 64);
    tsB.x += __shfl_xor(tsB.x, dd, 64); tsB.y += __shfl_xor(tsB.y, dd, 64);
  }
  if ((tid & 63) < 4) {
    float4 st; st.x = tsA.x; st.y = tsA.y; st.z = tsB.x; st.w = tsB.y;
    *(float4*)&red[(tid >> 6) * 16 + oq * 4] = st;
  }
  __syncthreads();
  if (tid < 16)
    feats[n * 16 + tid] =
        (red[tid] + red[16 + tid] + red[32 + tid] + red[48 + tid]) * (1.f / 500.f);
}

// ---------------------------------------------------------------------------
// GAT layer (R6 structure — the best-measured tail). Grid 256 = (b, i-half);
// block 512 = (head-half th) x 256. Fused per-block graph build. Row softmax:
// 8 lanes/row, shfl width 8, barrier-free head loop.
template <int FIN, int LAYER>
__global__ __launch_bounds__(512) void gat_kernel(
    const float* __restrict__ Xa,
    const float* __restrict__ node_embed, const int* __restrict__ edges,
    const float* __restrict__ se_w1, const float* __restrict__ se_w2,
    const float* __restrict__ gsum_in,
    const float* __restrict__ W, const float* __restrict__ a_src,
    const float* __restrict__ a_dst, const float* __restrict__ bias,
    const float* __restrict__ bnp, const float* __restrict__ skip_w,
    float* __restrict__ out, float* __restrict__ gsum_out)
{
  constexpr int XLS = 0;                 // 8448 (ne aliased in [0,1024) pre-proj)
  constexpr int AL  = 8448;              // 2 x 32 x 66 = 4224
  constexpr int MLG = AL + 4224;         // 32 x 66 = 2112 (counts -> log-mult)
  constexpr int XS  = MLG + 2112;        // 64*FIN
  constexpr int SS  = XS + 64 * FIN;     // 4 x 64
  constexpr int DS  = SS + 256;          // 32 x 4
  constexpr int CMB = DS + 128;          // 256 x 4
  constexpr int RS  = CMB + 1024;        // 32
  constexpr int SEA = RS + 32;           // 32
  constexpr int GT  = SEA + 32;          // 32
  constexpr int R8  = GT + 32;           // 8
  constexpr int TOT = R8 + 8;
  __shared__ float sm[TOT];

  const int b = blockIdx.x >> 1;
  const int i0 = (blockIdx.x & 1) * 32;
  const int tid = threadIdx.x;
  const int th = tid >> 8;               // head-half
  const int tl = tid & 255;

  // ---- P0: zero + loads ----
  if (tid < 32) sm[SEA + tid] = 0.f;
  if (LAYER == 2 && tid >= 32 && tid < 64)
    sm[GT + tid - 32] = gsum_in[tid - 32] * (1.f / 8192.f);
  for (int i = tid; i < 1024; i += 512) sm[XLS + i] = node_embed[i];
  for (int i = tid; i < 2112; i += 512) sm[MLG + i] = 0.f;
  for (int i = tid; i < 64 * FIN; i += 512) sm[XS + i] = Xa[b * 64 * FIN + i];
  int e0 = 0, e1 = 0;
  if (tid < 256) { e0 = edges[tid]; e1 = edges[256 + tid]; }
  __syncthreads();

  // ---- P1: A-half = relu(ne[i0+ir] . ne[j]); edge scatter; SE hidden ----
  for (int idx = tid; idx < 2048; idx += 512) {
    int ir = idx >> 6, j = idx & 63;
    const float* ni = sm + XLS + (i0 + ir) * 16;
    const float* nj = sm + XLS + j * 16;
    float a = 0.f;
#pragma unroll
    for (int f = 0; f < 16; ++f) a += ni[f] * nj[f];
    sm[AL + ir * 66 + j] = a > 0.f ? a : 0.f;
  }
  if (tid < 256 && e0 >= i0 && e0 < i0 + 32)
    atomicAdd(&sm[MLG + (e0 - i0) * 66 + e1], 1.f);
  if (LAYER == 2 && tid >= 256 && tid < 264) {
    float a = 0.f;
    for (int f = 0; f < 32; ++f) a += sm[GT + f] * se_w1[(tid - 256) * 32 + f];
    sm[R8 + tid - 256] = fmaxf(a, 0.f);
  }
  __syncthreads();

  // ---- P2: row sums of A; SE gate ----
  if (tid < 32) {
    float s = 0.f;
    for (int j = 0; j < 64; ++j) s += sm[AL + tid * 66 + j];
    sm[RS + tid] = s + 1e-6f;
  }
  if (LAYER == 2 && tid >= 256 && tid < 288) {
    float a = 0.f;
    for (int k = 0; k < 8; ++k) a += sm[R8 + k] * se_w2[(tid - 256) * 8 + k];
    sm[GT + tid - 256] = 1.f / (1.f + __expf(-a));
  }
  __syncthreads();

  // ---- P3: Mlg in place; gate Xs (layer 2) ----
  for (int idx = tid; idx < 2048; idx += 512) {
    int ir = idx >> 6, j = idx & 63;
    float dyn = (sm[AL + ir * 66 + j] / sm[RS + ir] > 0.1f) ? 1.f : 0.f;
    float M = (i0 + ir == j) ? 1.f : (sm[MLG + ir * 66 + j] + dyn);
    sm[MLG + ir * 66 + j] = (M > 0.f) ? __logf(M) : -INFINITY;
  }
  if (LAYER == 2) {
    for (int i = tid; i < 64 * FIN; i += 512) sm[XS + i] *= sm[GT + (i & 31)];
  }
  __syncthreads();

  // ---- P4: xl = X W (pitch 132), 16 rows/thread ----
  {
    const int fo = tid & 127, q4r = tid >> 7;
    float wcol[FIN];
#pragma unroll
    for (int q = 0; q < FIN; ++q) wcol[q] = W[q * 128 + fo];
    for (int nn = q4r; nn < 64; nn += 4) {
      float acc = 0.f;
#pragma unroll
      for (int q = 0; q < FIN; ++q) acc += sm[XS + nn * FIN + q] * wcol[q];
      sm[XLS + nn * 132 + fo] = acc;
    }
  }
  __syncthreads();

  // ---- P5: attention terms: s for all j, d for the i-half ----
  if (tid < 256) {
    const int nn = tid >> 2, h = tid & 3;
    float s = 0.f;
    for (int q = 0; q < 32; ++q)
      s += sm[XLS + nn * 132 + h * 32 + q] * a_src[h * 32 + q];
    sm[SS + h * 64 + nn] = s;
  } else if (tid < 384) {
    const int idx = tid - 256, ir = idx >> 2, h = idx & 3;
    float d = 0.f;
    for (int q = 0; q < 32; ++q)
      d += sm[XLS + (i0 + ir) * 132 + h * 32 + q] * a_dst[h * 32 + q];
    sm[DS + ir * 4 + h] = d;
  }
  __syncthreads();

  // ---- P6: head loop (2 heads per thread-half), barrier-free ----
  const int ir = tl >> 3;                // row 0..31
  const int q4 = tl & 7;                 // f-quad / j-chunk
  float* alw = sm + AL + th * 2112;
  float accT[4] = {0.f, 0.f, 0.f, 0.f};
#pragma unroll
  for (int hh = 0; hh < 2; ++hh) {
    const int h = hh * 2 + th;
    const float dterm = sm[DS + ir * 4 + h];
    float lg[8];
    float mx = -INFINITY;
#pragma unroll
    for (int k = 0; k < 8; ++k) {
      int j = q4 * 8 + k;
      float e = dterm + sm[SS + h * 64 + j];
      e = e >= 0.f ? e : 0.2f * e;
      float v = e + sm[MLG + ir * 66 + j];
      lg[k] = v;
      mx = fmaxf(mx, v);
    }
    mx = fmaxf(mx, __shfl_xor(mx, 1, 8));
    mx = fmaxf(mx, __shfl_xor(mx, 2, 8));
    mx = fmaxf(mx, __shfl_xor(mx, 4, 8));
    float sum = 0.f;
#pragma unroll
    for (int k = 0; k < 8; ++k) { lg[k] = __expf(lg[k] - mx); sum += lg[k]; }
    sum += __shfl_xor(sum, 1, 8);
    sum += __shfl_xor(sum, 2, 8);
    sum += __shfl_xor(sum, 4, 8);
    const float inv = 1.f / sum;
#pragma unroll
    for (int k = 0; k < 8; ++k) alw[ir * 66 + q4 * 8 + k] = lg[k];
    // readers are the same 8 lanes (lockstep wave) -> no barrier needed
    float a0 = 0.f, a1 = 0.f, a2 = 0.f, a3 = 0.f;
#pragma unroll 8
    for (int j = 0; j < 64; ++j) {
      float av = alw[ir * 66 + j];
      float4 xv = *(const float4*)&sm[XLS + j * 132 + h * 32 + q4 * 4];
      a0 += av * xv.x; a1 += av * xv.y; a2 += av * xv.z; a3 += av * xv.w;
    }
    accT[0] += a0 * inv; accT[1] += a1 * inv;
    accT[2] += a2 * inv; accT[3] += a3 * inv;
  }

  // ---- P7: combine thread-halves, epilogue on th==0 ----
  if (th == 1) *(float4*)&sm[CMB + tl * 4] = make_float4(accT[0], accT[1], accT[2], accT[3]);
  __syncthreads();
  if (th == 0) {
    const float4 other = *(const float4*)&sm[CMB + tl * 4];
    accT[0] += other.x; accT[1] += other.y; accT[2] += other.z; accT[3] += other.w;
    const int i = i0 + ir;
    float res[4];
#pragma unroll
    for (int r = 0; r < 4; ++r) {
      int f = q4 * 4 + r;
      float bsc = bnp[f] * rsqrtf(bnp[96 + f] + 1e-5f);
      float bsh = bnp[32 + f] - bnp[64 + f] * bsc;
      float v = accT[r] * 0.25f + bias[f];
      v = v * bsc + bsh;
      float skip;
      if (LAYER == 1) {
        skip = 0.f;
#pragma unroll
        for (int q = 0; q < 16; ++q) skip += sm[XS + i * 16 + q] * skip_w[f * 16 + q];
      } else {
        skip = sm[XS + i * 32 + f];
      }
      v += skip;
      v = 0.5f * v * (1.f + erff(v * 0.70710678118654752440f));
      res[r] = v;
      atomicAdd(&sm[SEA + f], v);
    }
    *(float4*)&out[(b * 64 + i) * 32 + q4 * 4] = make_float4(res[0], res[1], res[2], res[3]);
  }
  __syncthreads();
  if (tid < 32) atomicAdd(&gsum_out[tid], sm[SEA + tid]);
}

// ---------------------------------------------------------------------------
// SE2 gate (redundant per block) + pool over C + classifier.
__global__ __launch_bounds__(64) void out_kernel(
    const float* __restrict__ tmp2, const float* __restrict__ gsum2,
    const float* __restrict__ se_w1, const float* __restrict__ se_w2,
    const float* __restrict__ clf_w, const float* __restrict__ clf_b,
    float* __restrict__ outp)
{
  __shared__ float mean32[32], r8[8], gate[32], pl[32];
  const int b = blockIdx.x, tid = threadIdx.x;
  if (tid < 32) mean32[tid] = gsum2[tid] * (1.f / 8192.f);
  __syncthreads();
  if (tid < 8) {
    float a = 0.f;
    for (int f = 0; f < 32; ++f) a += mean32[f] * se_w1[tid * 32 + f];
    r8[tid] = a > 0.f ? a : 0.f;
  }
  __syncthreads();
  if (tid < 32) {
    float a = 0.f;
    for (int k = 0; k < 8; ++k) a += r8[k] * se_w2[tid * 8 + k];
    gate[tid] = 1.f / (1.f + __expf(-a));
  }
  __syncthreads();
  if (tid < 32) {
    float a = 0.f;
    for (int n = 0; n < 64; ++n) a += tmp2[(b * 64 + n) * 32 + tid];
    pl[tid] = a * (1.f / 64.f) * gate[tid];
  }
  __syncthreads();
  if (tid < 2) {
    float a = clf_b[tid];
    for (int f = 0; f < 32; ++f) a += pl[f] * clf_w[tid * 32 + f];
    outp[b * 2 + tid] = a;
  }
}

// ---------------------------------------------------------------------------
extern "C" void kernel_launch(void* const* d_in, const int* in_sizes, int n_in,
                              void* d_out, int out_size, void* d_ws, size_t ws_size,
                              hipStream_t stream)
{
  const float* x          = (const float*)d_in[0];
  const int*   edges      = (const int*)d_in[1];
  const float* conv1_w    = (const float*)d_in[2];
  const float* bn_c1      = (const float*)d_in[3];
  const float* dw_w       = (const float*)d_in[4];
  const float* bn_c2      = (const float*)d_in[5];
  const float* sdw_w      = (const float*)d_in[6];
  const float* spw_w      = (const float*)d_in[7];
  const float* bn_c3      = (const float*)d_in[8];
  const float* node_embed = (const float*)d_in[9];
  const float* gat1_w     = (const float*)d_in[10];
  const float* gat1_asrc  = (const float*)d_in[11];
  const float* gat1_adst  = (const float*)d_in[12];
  const float* gat1_bias  = (const float*)d_in[13];
  const float* bn_g1      = (const float*)d_in[14];
  const float* skip1_w    = (const float*)d_in[15];
  const float* se1_w1     = (const float*)d_in[16];
  const float* se1_w2     = (const float*)d_in[17];
  const float* gat2_w     = (const float*)d_in[18];
  const float* gat2_asrc  = (const float*)d_in[19];
  const float* gat2_adst  = (const float*)d_in[20];
  const float* gat2_bias  = (const float*)d_in[21];
  const float* bn_g2      = (const float*)d_in[22];
  const float* se2_w1     = (const float*)d_in[23];
  const float* se2_w2     = (const float*)d_in[24];
  const float* clf_w      = (const float*)d_in[25];
  const float* clf_b      = (const float*)d_in[26];

  float* ws    = (float*)d_ws;
  float* feats = ws;             // 131072 floats  [B*C, 16]
  float* tmp1  = ws + 131072;    // 262144         [B*C, 32]
  float* tmp2  = ws + 393216;    // 262144         [B*C, 32]
  float* gs    = ws + 655360;    // 64: gsum1[32] | gsum2[32]

  feat_kernel<<<Bn * Cn, 256, 0, stream>>>(x, conv1_w, bn_c1, dw_w, bn_c2,
                                           sdw_w, spw_w, bn_c3, feats, gs);
  gat_kernel<16, 1><<<Bn * 2, 512, 0, stream>>>(
      feats, node_embed, edges, nullptr, nullptr, nullptr,
      gat1_w, gat1_asrc, gat1_adst, gat1_bias, bn_g1, skip1_w, tmp1, gs);
  gat_kernel<32, 2><<<Bn * 2, 512, 0, stream>>>(
      tmp1, node_embed, edges, se1_w1, se1_w2, gs,
      gat2_w, gat2_asrc, gat2_adst, gat2_bias, bn_g2, nullptr, tmp2, gs + 32);
  out_kernel<<<Bn, 64, 0, stream>>>(tmp2, gs + 32, se2_w1, se2_w2, clf_w, clf_b,
                                    (float*)d_out);
}